// Round 3
// baseline (201.194 us; speedup 1.0000x reference)
//
#include <hip/hip_runtime.h>

#define T_DIM 2048
#define B_DIM 16
#define C_DIM 512
#define NW 56            // H*K

// ---- LDS map: xs (bf16 22x512, swizzled) + wt (fp32 16x56)
#define XS_BYTES (22 * 512 * 2)       // 22528 B
#define WT_OFF   XS_BYTES
#define F_LDS    (XS_BYTES + 3584)    // 26112 B -> 6 blocks/CU

typedef __attribute__((ext_vector_type(8))) short short8;
typedef __attribute__((ext_vector_type(4))) float floatx4;

static __device__ __forceinline__ unsigned short f2bf(float x) {
    union { float f; unsigned u; } v; v.f = x;
    return (unsigned short)((v.u + 0x7FFFu + ((v.u >> 16) & 1u)) >> 16);  // RNE
}
static __device__ __forceinline__ float bf_lo(unsigned u) {
    union { unsigned u; float f; } c; c.u = u << 16; return c.f;
}
static __device__ __forceinline__ float bf_hi(unsigned u) {
    union { unsigned u; float f; } c; c.u = u & 0xFFFF0000u; return c.f;
}
// 16B-block XOR swizzle for the bf16 xs layout: bank-group bits [6:4] ^= addr[9:7].
static __device__ __forceinline__ int swz(int a) { return a ^ ((a >> 3) & 0x70); }

// ---------------------------------------------------------------------------
// Pre-kernel: pack W (512x56 fp32) into bf16 MFMA B-fragments, HEAD-PACKED:
// n-tile nt covers global cols n = nt*14 + c for c in 0..13 (heads 2nt, 2nt+1);
// cols c = 14,15 are zero-pad. This puts every softmax group of 7 inside one
// wave's 16-col tile so softmax needs no cross-wave exchange.
// Bg[(ks*4+nt)*64 + l][j] = W[k = ks*32+((l>>4)&3)*8+j][n], l&15 = c.
// ---------------------------------------------------------------------------
__global__ __launch_bounds__(256)
void pack_w(const float* __restrict__ W, short8* __restrict__ Bg) {
    const int g  = blockIdx.x * 256 + threadIdx.x;   // 0..4095
    const int ks = g >> 8;
    const int nt = (g >> 6) & 3;
    const int l  = g & 63;
    const int c  = l & 15;
    const int n  = nt * 14 + c;
    const int k0 = ks * 32 + ((l >> 4) & 3) * 8;
    short8 o;
#pragma unroll
    for (int j = 0; j < 8; ++j) {
        const float v = (c < 14) ? W[(size_t)(k0 + j) * NW + n] : 0.f;
        o[j] = (short)f2bf(v);
    }
    Bg[g] = o;
}

// ---------------------------------------------------------------------------
// Fused one-barrier kernel. Block = 16 t x 1 b, 4 waves.
// Phase 1: GEMM — each wave loads the FULL A tile per-lane straight from q
//          (fragment order, L2-hot duplicates), B frags rolling from global.
// Phase 2: in-wave softmax (head-packed cols) -> wt LDS (no barrier needed).
// Phase 3: x window loads -> bf16 swizzled xs in LDS.
// Phase 4: ONE __syncthreads().
// Phase 5: conv + nontemporal stores.
// ---------------------------------------------------------------------------
__global__ __launch_bounds__(256)
void fused1(const float* __restrict__ x, const float* __restrict__ q,
            const short8* __restrict__ Bg, float* __restrict__ out) {
    __shared__ __align__(16) char S[F_LDS];

    const int tid  = threadIdx.x;
    const int lane = tid & 63;
    const int wv   = tid >> 6;                 // wave id = n-tile
    const int b    = blockIdx.x & 15;
    const int t0   = (blockIdx.x >> 4) * 16;

    // ---- Phase 1: logits GEMM (16 MFMAs, rolling loads)
    const int rq = lane & 15;                  // A row (= t within tile)
    const int qq = lane >> 4;                  // quad -> k sub-offset
    const float* qbase = q + ((size_t)(t0 + rq) * B_DIM + b) * C_DIM + qq * 8;
    floatx4 acc = (floatx4){0.f, 0.f, 0.f, 0.f};
#pragma unroll 4
    for (int ks = 0; ks < 16; ++ks) {
        const float4 f0 = *(const float4*)(qbase + ks * 32);
        const float4 f1 = *(const float4*)(qbase + ks * 32 + 4);
        const short8 bf = Bg[(ks * 4 + wv) * 64 + lane];
        short8 af;
        af[0] = (short)f2bf(f0.x); af[1] = (short)f2bf(f0.y);
        af[2] = (short)f2bf(f0.z); af[3] = (short)f2bf(f0.w);
        af[4] = (short)f2bf(f1.x); af[5] = (short)f2bf(f1.y);
        af[6] = (short)f2bf(f1.z); af[7] = (short)f2bf(f1.w);
        acc = __builtin_amdgcn_mfma_f32_16x16x32_bf16(af, bf, acc, 0, 0, 0);
    }

    // ---- Phase 2: in-wave softmax. acc[r] = logit[row=quad*4+r][n=wv*14+c]
    const int c    = lane & 15;
    const int cb   = (c < 7) ? 0 : 7;          // head base col within tile
    const int sb   = (lane & 48) + cb;         // shfl source lane base
    const int quad = lane >> 4;
    float* wt = (float*)(S + WT_OFF);
#pragma unroll
    for (int r = 0; r < 4; ++r) {
        const float a = acc[r];
        const float v0 = __shfl(a, sb + 0);
        const float v1 = __shfl(a, sb + 1);
        const float v2 = __shfl(a, sb + 2);
        const float v3 = __shfl(a, sb + 3);
        const float v4 = __shfl(a, sb + 4);
        const float v5 = __shfl(a, sb + 5);
        const float v6 = __shfl(a, sb + 6);
        const float mx = fmaxf(fmaxf(fmaxf(v0, v1), fmaxf(v2, v3)),
                               fmaxf(fmaxf(v4, v5), v6));
        const float sm = __expf(v0 - mx) + __expf(v1 - mx) + __expf(v2 - mx) +
                         __expf(v3 - mx) + __expf(v4 - mx) + __expf(v5 - mx) +
                         __expf(v6 - mx);
        const float w = __expf(a - mx) * (1.0f / sm);
        if (c < 14)
            wt[(quad * 4 + r) * NW + wv * 14 + c] = w;
    }

    // keep the x loads from being hoisted above the GEMM (VGPR control)
    __builtin_amdgcn_sched_barrier(0);

    // ---- Phase 3: x window loads (22 padded rows x 512 fp32) -> xs
    char* XS = S;
#pragma unroll
    for (int j = 0; j < 11; ++j) {
        const int idx = tid + j * 256;         // float4 index 0..2815
        const int i   = idx >> 7;              // padded row 0..21
        const int cc  = (idx & 127) * 4;
        const int tp  = t0 + i - 3;
        float4 xv = make_float4(0.f, 0.f, 0.f, 0.f);
        if (tp >= 0 && tp < T_DIM)
            xv = *(const float4*)(x + ((size_t)tp * B_DIM + b) * C_DIM + cc);
        uint2 p;
        p.x = (unsigned)f2bf(xv.x) | ((unsigned)f2bf(xv.y) << 16);
        p.y = (unsigned)f2bf(xv.z) | ((unsigned)f2bf(xv.w) << 16);
        *(uint2*)(XS + swz(idx * 8)) = p;
    }

    // ---- Phase 4: the single barrier (publishes xs + wt)
    __syncthreads();

    // ---- Phase 5: conv — lane owns outputs 8l..8l+8 = window bytes [112l,112l+112)
    const int h = lane >> 3;
    const int base_b = lane * 112;
#pragma unroll
    for (int s = 0; s < 4; ++s) {
        const int tt = wv * 4 + s;
        const int tb = tt * 1024 + base_b;
        uint4 xu[7];
#pragma unroll
        for (int i = 0; i < 7; ++i)
            xu[i] = *(const uint4*)(XS + swz(tb + i * 16));
        float xf[56];
#pragma unroll
        for (int i = 0; i < 7; ++i) {
            xf[i * 8 + 0] = bf_lo(xu[i].x); xf[i * 8 + 1] = bf_hi(xu[i].x);
            xf[i * 8 + 2] = bf_lo(xu[i].y); xf[i * 8 + 3] = bf_hi(xu[i].y);
            xf[i * 8 + 4] = bf_lo(xu[i].z); xf[i * 8 + 5] = bf_hi(xu[i].z);
            xf[i * 8 + 6] = bf_lo(xu[i].w); xf[i * 8 + 7] = bf_hi(xu[i].w);
        }
        const float* wp = wt + tt * NW + h * 7;
        float w[7];
#pragma unroll
        for (int k = 0; k < 7; ++k) w[k] = wp[k];
        float a8[8];
#pragma unroll
        for (int r = 0; r < 8; ++r) {
            float sacc = xf[r * 7] * w[0];
#pragma unroll
            for (int k = 1; k < 7; ++k) sacc = fmaf(w[k], xf[r * 7 + k], sacc);
            a8[r] = sacc;
        }
        float* orow = out + ((size_t)(t0 + tt) * B_DIM + b) * C_DIM + lane * 8;
        floatx4 v0 = (floatx4){a8[0], a8[1], a8[2], a8[3]};
        floatx4 v1 = (floatx4){a8[4], a8[5], a8[6], a8[7]};
        __builtin_nontemporal_store(v0, (floatx4*)orow);
        __builtin_nontemporal_store(v1, (floatx4*)(orow + 4));
    }
}

extern "C" void kernel_launch(void* const* d_in, const int* in_sizes, int n_in,
                              void* d_out, int out_size, void* d_ws, size_t ws_size,
                              hipStream_t stream) {
    const float* x = (const float*)d_in[0];
    const float* q = (const float*)d_in[1];
    const float* W = (const float*)d_in[2];
    float* out = (float*)d_out;
    short8* Bg = (short8*)d_ws;   // 64 KB packed bf16 B-fragments (head-packed)

    pack_w<<<16, 256, 0, stream>>>(W, Bg);
    fused1<<<(T_DIM / 16) * B_DIM, 256, 0, stream>>>(x, q, Bg, out);
}